// Round 1
// baseline (144.380 us; speedup 1.0000x reference)
//
#include <hip/hip_runtime.h>

typedef unsigned int uint;
typedef _Float16 f16;

typedef __attribute__((ext_vector_type(8))) _Float16 f16x8;
typedef __attribute__((ext_vector_type(2))) _Float16 f16x2;
typedef __attribute__((ext_vector_type(4))) float f32x4;

#define E_CNT 496

__device__ __forceinline__ uint pack2_f16(float lo, float hi) {
    union { f16x2 h; uint u; } r;
    r.h[0] = (_Float16)lo;
    r.h[1] = (_Float16)hi;
    return r.u;
}

// ---------------- X staging via swapped-operand MFMA; W1 frags in registers --
// grid = 512 (= 128 rowblocks x 4 ngroups); block = 256 thr = 4 waves.
// Wave owns 2 n-tiles (32 of the 512 output cols) for 64 rows.
// A-operand = W1 rows (16 h), B-operand = hidden rows -> D[h][row]:
// lane(quad,l16): col=l16 = hidden row, rows quad*4+r = h offsets -> 8B stores.
__global__ __launch_bounds__(256) void x_kernel(
    const float* __restrict__ hidden, const float* __restrict__ W1,
    const float* __restrict__ b1, f16* __restrict__ Xout) {
    __shared__ __align__(16) float hs[64 * 132];  // padded stride 132 -> b128 at floor

    const int tid = threadIdx.x;
    const int rowblock = blockIdx.x >> 2;
    const int g = blockIdx.x & 3;
    const int ln = tid & 63;
    const int waveId = tid >> 6;
    const int quad = ln >> 4;
    const int l16 = ln & 15;
    const int row0 = rowblock * 64;

    // W1 A-frags for this wave's 2 n-tiles (held in regs, f32->f16 inline)
    union FU { uint u[4]; f16x8 v; };
    FU wf[2][4];
    float bh[2][4];
    #pragma unroll
    for (int nt = 0; nt < 2; ++nt) {
        const int t = (g * 4 + waveId) * 2 + nt;   // ntile 0..31
        const int half = t >> 4;
        const int htile = t & 15;
        const float* wrow = W1 + (htile * 16 + l16) * 256 + half * 128 + quad * 8;
        #pragma unroll
        for (int kk = 0; kk < 4; ++kk) {
            float4 v0 = *(const float4*)(wrow + kk * 32);
            float4 v1 = *(const float4*)(wrow + kk * 32 + 4);
            wf[nt][kk].u[0] = pack2_f16(v0.x, v0.y);
            wf[nt][kk].u[1] = pack2_f16(v0.z, v0.w);
            wf[nt][kk].u[2] = pack2_f16(v1.x, v1.y);
            wf[nt][kk].u[3] = pack2_f16(v1.z, v1.w);
        }
        #pragma unroll
        for (int r = 0; r < 4; ++r)
            bh[nt][r] = 0.5f * b1[htile * 16 + quad * 4 + r];
    }

    // stage 64 hidden rows into LDS (coalesced float4)
    {
        const float* src = hidden + row0 * 128;
        #pragma unroll
        for (int it = 0; it < 8; ++it) {
            int idx = it * 256 + tid;      // float4 index 0..2047
            int r = idx >> 5;
            int c4 = idx & 31;
            float4 v = *(const float4*)(src + idx * 4);
            *(float4*)&hs[r * 132 + c4 * 4] = v;
        }
    }
    __syncthreads();

    #pragma unroll
    for (int ch = 0; ch < 4; ++ch) {
        // hidden B-frags from LDS (shared by both n-tiles)
        FU hf[4];
        const float* hrow = &hs[(ch * 16 + l16) * 132 + quad * 8];
        #pragma unroll
        for (int kk = 0; kk < 4; ++kk) {
            float4 v0 = *(const float4*)(hrow + kk * 32);
            float4 v1 = *(const float4*)(hrow + kk * 32 + 4);
            hf[kk].u[0] = pack2_f16(v0.x, v0.y);
            hf[kk].u[1] = pack2_f16(v0.z, v0.w);
            hf[kk].u[2] = pack2_f16(v1.x, v1.y);
            hf[kk].u[3] = pack2_f16(v1.z, v1.w);
        }
        #pragma unroll
        for (int nt = 0; nt < 2; ++nt) {
            const int t = (g * 4 + waveId) * 2 + nt;
            const int half = t >> 4;
            const int htile = t & 15;
            f32x4 acc = (f32x4){0.f, 0.f, 0.f, 0.f};
            #pragma unroll
            for (int kk = 0; kk < 4; ++kk)
                acc = __builtin_amdgcn_mfma_f32_16x16x32_f16(wf[nt][kk].v, hf[kk].v, acc, 0, 0, 0);
            uint2 o;
            o.x = pack2_f16(acc[0] + bh[nt][0], acc[1] + bh[nt][1]);
            o.y = pack2_f16(acc[2] + bh[nt][2], acc[3] + bh[nt][3]);
            f16* dst = Xout + half * (8192 * 256)
                     + (row0 + ch * 16 + l16) * 256 + htile * 16 + quad * 4;
            *(uint2*)dst = o;
        }
    }
}

// ---------------- fused GEMM2 (MFMA, fp16) + payoff ----------------
// block = 256 thr = 4 waves; 64 pairs/block; grid 1984 XCD-swizzled.
// W2 staged as two k-halves [96][136] f16 (26112 B) -> LDS 26.1 KB
// -> 4 blocks/CU at the 16-wave register cap (better phase stagger).
#define PAIR_STRIDE 100
#define R_OFF 800
#define WAVE_PF 1600

__global__ __launch_bounds__(256, 4) void gemm_payoff_kernel(
    const f16* __restrict__ X1, const f16* __restrict__ X2,
    const int* __restrict__ e_f, const int* __restrict__ e_t,
    const float* __restrict__ W2, const float* __restrict__ b2,
    float* __restrict__ out) {

    __shared__ __align__(16) unsigned char smem[26624];
    f16* w2s = (f16*)smem;    // phase 1: W2 k-half f16 [96][136] = 26112 B
    float* pf = (float*)smem; // phase 2: per-wave 1600 floats x 4 = 25600 B

    const int tid = threadIdx.x;
    const int ln = tid & 63;
    const int waveId = tid >> 6;
    const int quad = ln >> 4;
    const int l16 = ln & 15;
    const int pl = l16 & 7;
    const int s = l16 >> 3;

    // XCD swizzle: 1984 = 8 * 248 (bijective)
    const int bx = blockIdx.x;
    const int lb = (bx & 7) * 248 + (bx >> 3);

    // edge dtype detect (uniform -> scalar loads)
    bool f64 = true, t64 = true;
    #pragma unroll
    for (int i = 0; i < 16; ++i) {
        if (e_f[2 * i + 1] != 0) f64 = false;
        if (e_t[2 * i + 1] != 0) t64 = false;
    }

    const int pairBase = lb * 64 + waveId * 16;
    const f16* px1[2];
    const f16* px2[2];
    #pragma unroll
    for (int mt = 0; mt < 2; ++mt) {
        int pair = pairBase + mt * 8 + pl;
        int b = pair / E_CNT;
        int e = pair - b * E_CNT;
        int f = f64 ? e_f[2 * e] : e_f[e];
        int t = t64 ? e_t[2 * e] : e_t[e];
        int n1 = s ? t : f;
        int n2 = s ? f : t;
        px1[mt] = X1 + ((b * 32 + n1) * 256 + quad * 8);
        px2[mt] = X2 + ((b * 32 + n2) * 256 + quad * 8);
    }

    f32x4 acc[2][6];
    #pragma unroll
    for (int mt = 0; mt < 2; ++mt)
        #pragma unroll
        for (int tt = 0; tt < 6; ++tt) acc[mt][tt] = (f32x4){0.f, 0.f, 0.f, 0.f};

    typedef union { uint4 q; f16x8 h; } XU;
    XU G1[2][2], G2[2][2];  // [buf][mt]

    #pragma unroll
    for (int mt = 0; mt < 2; ++mt) {
        G1[0][mt].q = *(const uint4*)(px1[mt] + 0 * 32);
        G2[0][mt].q = *(const uint4*)(px2[mt] + 0 * 32);
        G1[1][mt].q = *(const uint4*)(px1[mt] + 1 * 32);
        G2[1][mt].q = *(const uint4*)(px2[mt] + 1 * 32);
    }

    // stage W2 k-half h: [96][136] f16, 12 float4/thread
    auto stageW2 = [&](int h) {
        #pragma unroll
        for (int j = 0; j < 12; ++j) {
            int idx4 = tid + j * 256;   // 0..3071
            int n = idx4 >> 5;          // row 0..95
            int k4 = idx4 & 31;         // float4 within the 128-wide half
            float4 v = *(const float4*)&W2[n * 256 + h * 128 + k4 * 4];
            uint2 o;
            o.x = pack2_f16(v.x, v.y);
            o.y = pack2_f16(v.z, v.w);
            *(uint2*)&w2s[n * 136 + k4 * 4] = o;
        }
    };

    const f16x8 zero8 = (f16x8){0, 0, 0, 0, 0, 0, 0, 0};

    stageW2(0);
    __syncthreads();

    // kk 0..3 on k-half 0; prefetch keeps the 2-deep pipeline across the split
    #pragma unroll
    for (int kk = 0; kk < 4; ++kk) {
        const int buf = kk & 1;
        f16x8 af[2];
        #pragma unroll
        for (int mt = 0; mt < 2; ++mt) {
            f16x8 sum = G1[buf][mt].h + G2[buf][mt].h;
            af[mt] = __builtin_elementwise_max(sum, zero8);
        }
        #pragma unroll
        for (int mt = 0; mt < 2; ++mt) {   // loads kk 2,3,4,5
            G1[buf][mt].q = *(const uint4*)(px1[mt] + (kk + 2) * 32);
            G2[buf][mt].q = *(const uint4*)(px2[mt] + (kk + 2) * 32);
        }
        #pragma unroll
        for (int tt = 0; tt < 6; ++tt) {
            f16x8 bf = *(const f16x8*)&w2s[(tt * 16 + l16) * 136 + kk * 32 + quad * 8];
            acc[0][tt] = __builtin_amdgcn_mfma_f32_16x16x32_f16(af[0], bf, acc[0][tt], 0, 0, 0);
            acc[1][tt] = __builtin_amdgcn_mfma_f32_16x16x32_f16(af[1], bf, acc[1][tt], 0, 0, 0);
        }
    }

    __syncthreads();   // all waves done reading k-half 0
    stageW2(1);
    __syncthreads();

    // kk 4..7 on k-half 1
    #pragma unroll
    for (int kk = 4; kk < 8; ++kk) {
        const int buf = kk & 1;
        f16x8 af[2];
        #pragma unroll
        for (int mt = 0; mt < 2; ++mt) {
            f16x8 sum = G1[buf][mt].h + G2[buf][mt].h;
            af[mt] = __builtin_elementwise_max(sum, zero8);
        }
        if (kk < 6) {
            #pragma unroll
            for (int mt = 0; mt < 2; ++mt) {
                G1[buf][mt].q = *(const uint4*)(px1[mt] + (kk + 2) * 32);
                G2[buf][mt].q = *(const uint4*)(px2[mt] + (kk + 2) * 32);
            }
        }
        #pragma unroll
        for (int tt = 0; tt < 6; ++tt) {
            f16x8 bf = *(const f16x8*)&w2s[(tt * 16 + l16) * 136 + (kk - 4) * 32 + quad * 8];
            acc[0][tt] = __builtin_amdgcn_mfma_f32_16x16x32_f16(af[0], bf, acc[0][tt], 0, 0, 0);
            acc[1][tt] = __builtin_amdgcn_mfma_f32_16x16x32_f16(af[1], bf, acc[1][tt], 0, 0, 0);
        }
    }

    float b2v[6];
    #pragma unroll
    for (int tt = 0; tt < 6; ++tt) b2v[tt] = b2[tt * 16 + l16];

    // hoisted dump-address precompute (mt-invariant, r enters as +r*PAIR_STRIDE)
    int doff[6];
    {
        const int s_ = quad >> 1;
        #pragma unroll
        for (int tt = 0; tt < 6; ++tt) {
            int n = tt * 16 + l16;
            int rr = n / 24;
            int rem = n - rr * 24;
            int c01 = (rem >= 12) ? 1 : 0;
            int a = rem - c01 * 12;
            int k8 = (s_ ? 4 : 0) + rr;
            int toL = (c01 == s_) ? 1 : 0;
            doff[tt] = (toL ? 0 : R_OFF) + (quad & 1) * 4 * PAIR_STRIDE + a * 8 + k8;
        }
    }

    __syncthreads();  // all waves done reading w2s; LDS repurposed per-wave

    float* wbase = pf + waveId * WAVE_PF;
    #pragma unroll
    for (int mt = 0; mt < 2; ++mt) {
        // dump p (+b2) into payoff layout
        #pragma unroll
        for (int tt = 0; tt < 6; ++tt) {
            #pragma unroll
            for (int r = 0; r < 4; ++r) {
                wbase[doff[tt] + r * PAIR_STRIDE] = acc[mt][tt][r] + b2v[tt];
            }
        }

        // payoff: out[i][j] = 0.5 * sum_k8 L[i][k8]*R[j][k8]
        #pragma unroll
        for (int it = 0; it < 2; ++it) {
            int task = it * 64 + ln;
            if (task < 96) {
                int pp = task / 12;
                int i = task - pp * 12;
                const float* Lp = wbase + pp * PAIR_STRIDE + i * 8;
                float4 l0 = *(const float4*)&Lp[0];
                float4 l1 = *(const float4*)&Lp[4];
                float od[12];
                #pragma unroll
                for (int jj = 0; jj < 12; ++jj) {
                    const float* Rp = wbase + R_OFF + pp * PAIR_STRIDE + jj * 8;
                    float4 r0 = *(const float4*)&Rp[0];
                    float4 r1 = *(const float4*)&Rp[4];
                    float d = l0.x * r0.x + l0.y * r0.y + l0.z * r0.z + l0.w * r0.w
                            + l1.x * r1.x + l1.y * r1.y + l1.z * r1.z + l1.w * r1.w;
                    od[jj] = 0.5f * d;
                }
                int outBase = (pairBase + mt * 8 + pp) * 144 + i * 12;
                *(float4*)&out[outBase + 0] = make_float4(od[0], od[1], od[2], od[3]);
                *(float4*)&out[outBase + 4] = make_float4(od[4], od[5], od[6], od[7]);
                *(float4*)&out[outBase + 8] = make_float4(od[8], od[9], od[10], od[11]);
            }
        }
    }
}

extern "C" void kernel_launch(void* const* d_in, const int* in_sizes, int n_in,
                              void* d_out, int out_size, void* d_ws, size_t ws_size,
                              hipStream_t stream) {
    const float* hidden = (const float*)d_in[0];
    const float* W1 = (const float*)d_in[1];
    const float* b1 = (const float*)d_in[2];
    const float* W2 = (const float*)d_in[3];
    const float* b2 = (const float*)d_in[4];
    const int* e_f = (const int*)d_in[5];
    const int* e_t = (const int*)d_in[6];
    float* out = (float*)d_out;

    char* ws = (char*)d_ws;
    f16* X = (f16*)ws;   // X1 then X2, 4 MB each

    x_kernel<<<512, 256, 0, stream>>>(hidden, W1, b1, X);
    gemm_payoff_kernel<<<1984, 256, 0, stream>>>(X, X + 8192 * 256, e_f, e_t, W2, b2, out);
}

// Round 2
// 141.533 us; speedup vs baseline: 1.0201x; 1.0201x over previous
//
#include <hip/hip_runtime.h>

typedef unsigned int uint;
typedef _Float16 f16;

typedef __attribute__((ext_vector_type(8))) _Float16 f16x8;
typedef __attribute__((ext_vector_type(2))) _Float16 f16x2;
typedef __attribute__((ext_vector_type(4))) float f32x4;

#define E_CNT 496

// W2 f16 image geometry (row stride padded for LDS bank spread, 16B aligned)
#define W2_STRIDE 152                       // f16 units per row
#define W2_HALF_F16 (96 * W2_STRIDE)        // 14592
#define W2_HALF_BYTES (W2_HALF_F16 * 2)     // 29184
#define W2_CHUNKS 29                        // ceil(29184 / 1024)

__device__ __forceinline__ uint pack2_f16(float lo, float hi) {
    union { f16x2 h; uint u; } r;
    r.h[0] = (_Float16)lo;
    r.h[1] = (_Float16)hi;
    return r.u;
}

__device__ __forceinline__ void load_lds16(const void* g, void* l) {
    __builtin_amdgcn_global_load_lds(
        (const __attribute__((address_space(1))) void*)g,
        (__attribute__((address_space(3))) void*)l, 16, 0, 0);
}

// ---------------- X staging via swapped-operand MFMA; W1 frags in registers --
// grid = 513; blocks 0..511 = 128 rowblocks x 4 ngroups; block 512 converts W2.
__global__ __launch_bounds__(256) void x_kernel(
    const float* __restrict__ hidden, const float* __restrict__ W1,
    const float* __restrict__ b1, f16* __restrict__ Xout,
    const float* __restrict__ W2, f16* __restrict__ w2h) {
    __shared__ __align__(16) float hs[64 * 132];

    const int tid = threadIdx.x;

    if (blockIdx.x == 512) {
        // convert W2 f32 [96][256] -> f16 image [2][96][W2_STRIDE]
        #pragma unroll
        for (int j = 0; j < 24; ++j) {
            int idx4 = tid + j * 256;       // float4 index 0..6143
            int n = idx4 >> 6;
            int k = (idx4 & 63) << 2;
            int h = k >> 7;
            int kin = k & 127;
            float4 v = *(const float4*)&W2[n * 256 + k];
            uint2 o;
            o.x = pack2_f16(v.x, v.y);
            o.y = pack2_f16(v.z, v.w);
            *(uint2*)&w2h[h * W2_HALF_F16 + n * W2_STRIDE + kin] = o;
        }
        return;
    }

    const int rowblock = blockIdx.x >> 2;
    const int g = blockIdx.x & 3;
    const int ln = tid & 63;
    const int waveId = tid >> 6;
    const int quad = ln >> 4;
    const int l16 = ln & 15;
    const int row0 = rowblock * 64;

    union FU { uint u[4]; f16x8 v; };
    FU wf[2][4];
    float bh[2][4];
    #pragma unroll
    for (int nt = 0; nt < 2; ++nt) {
        const int t = (g * 4 + waveId) * 2 + nt;
        const int half = t >> 4;
        const int htile = t & 15;
        const float* wrow = W1 + (htile * 16 + l16) * 256 + half * 128 + quad * 8;
        #pragma unroll
        for (int kk = 0; kk < 4; ++kk) {
            float4 v0 = *(const float4*)(wrow + kk * 32);
            float4 v1 = *(const float4*)(wrow + kk * 32 + 4);
            wf[nt][kk].u[0] = pack2_f16(v0.x, v0.y);
            wf[nt][kk].u[1] = pack2_f16(v0.z, v0.w);
            wf[nt][kk].u[2] = pack2_f16(v1.x, v1.y);
            wf[nt][kk].u[3] = pack2_f16(v1.z, v1.w);
        }
        #pragma unroll
        for (int r = 0; r < 4; ++r)
            bh[nt][r] = 0.5f * b1[htile * 16 + quad * 4 + r];
    }

    {
        const float* src = hidden + row0 * 128;
        #pragma unroll
        for (int it = 0; it < 8; ++it) {
            int idx = it * 256 + tid;
            int r = idx >> 5;
            int c4 = idx & 31;
            float4 v = *(const float4*)(src + idx * 4);
            *(float4*)&hs[r * 132 + c4 * 4] = v;
        }
    }
    __syncthreads();

    #pragma unroll
    for (int ch = 0; ch < 4; ++ch) {
        FU hf[4];
        const float* hrow = &hs[(ch * 16 + l16) * 132 + quad * 8];
        #pragma unroll
        for (int kk = 0; kk < 4; ++kk) {
            float4 v0 = *(const float4*)(hrow + kk * 32);
            float4 v1 = *(const float4*)(hrow + kk * 32 + 4);
            hf[kk].u[0] = pack2_f16(v0.x, v0.y);
            hf[kk].u[1] = pack2_f16(v0.z, v0.w);
            hf[kk].u[2] = pack2_f16(v1.x, v1.y);
            hf[kk].u[3] = pack2_f16(v1.z, v1.w);
        }
        #pragma unroll
        for (int nt = 0; nt < 2; ++nt) {
            const int t = (g * 4 + waveId) * 2 + nt;
            const int half = t >> 4;
            const int htile = t & 15;
            f32x4 acc = (f32x4){0.f, 0.f, 0.f, 0.f};
            #pragma unroll
            for (int kk = 0; kk < 4; ++kk)
                acc = __builtin_amdgcn_mfma_f32_16x16x32_f16(wf[nt][kk].v, hf[kk].v, acc, 0, 0, 0);
            uint2 o;
            o.x = pack2_f16(acc[0] + bh[nt][0], acc[1] + bh[nt][1]);
            o.y = pack2_f16(acc[2] + bh[nt][2], acc[3] + bh[nt][3]);
            f16* dst = Xout + half * (8192 * 256)
                     + (row0 + ch * 16 + l16) * 256 + htile * 16 + quad * 4;
            *(uint2*)dst = o;
        }
    }
}

// ---------------- fused GEMM2 (MFMA, fp16) + MFMA payoff ----------------
// block = 256 thr = 4 waves; 64 pairs/block; grid 1984 XCD-swizzled.
// W2 staged per k-half via global_load_lds from the precomputed f16 image.
// Payoff: per pair one 16x16x32 MFMA with K=8 (quads 1-3 zero).
__global__ __launch_bounds__(256, 4) void gemm_payoff_kernel(
    const f16* __restrict__ X1, const f16* __restrict__ X2,
    const int* __restrict__ e_f, const int* __restrict__ e_t,
    const f16* __restrict__ w2g, const float* __restrict__ b2,
    float* __restrict__ out) {

    __shared__ __align__(16) unsigned char smem[32768];
    f16* w2s = (f16*)smem;

    const int tid = threadIdx.x;
    const int ln = tid & 63;
    const int waveId = tid >> 6;
    const int quad = ln >> 4;
    const int l16 = ln & 15;
    const int pl = l16 & 7;
    const int s = l16 >> 3;

    // XCD swizzle: 1984 = 8 * 248 (bijective)
    const int bx = blockIdx.x;
    const int lb = (bx & 7) * 248 + (bx >> 3);

    // stage W2 k-half via async direct-to-LDS (wave-uniform dest, lane x 16B)
    auto stageW2 = [&](int h) {
        const unsigned char* src = (const unsigned char*)w2g + h * W2_HALF_BYTES + ln * 16;
        #pragma unroll
        for (int j = 0; j < 8; ++j) {
            int i = waveId + j * 4;
            if (i < W2_CHUNKS)
                load_lds16(src + i * 1024, smem + i * 1024);
        }
    };

    stageW2(0);   // async; overlap setup below

    // edge dtype detect (uniform -> scalar loads)
    bool f64 = true, t64 = true;
    #pragma unroll
    for (int i = 0; i < 16; ++i) {
        if (e_f[2 * i + 1] != 0) f64 = false;
        if (e_t[2 * i + 1] != 0) t64 = false;
    }

    const int pairBase = lb * 64 + waveId * 16;
    const f16* px1[2];
    const f16* px2[2];
    #pragma unroll
    for (int mt = 0; mt < 2; ++mt) {
        int pair = pairBase + mt * 8 + pl;
        int b = pair / E_CNT;
        int e = pair - b * E_CNT;
        int f = f64 ? e_f[2 * e] : e_f[e];
        int t = t64 ? e_t[2 * e] : e_t[e];
        int n1 = s ? t : f;
        int n2 = s ? f : t;
        px1[mt] = X1 + ((b * 32 + n1) * 256 + quad * 8);
        px2[mt] = X2 + ((b * 32 + n2) * 256 + quad * 8);
    }

    f32x4 acc[2][6];
    #pragma unroll
    for (int mt = 0; mt < 2; ++mt)
        #pragma unroll
        for (int tt = 0; tt < 6; ++tt) acc[mt][tt] = (f32x4){0.f, 0.f, 0.f, 0.f};

    typedef union { uint4 q; f16x8 h; } XU;
    XU G1[2][2], G2[2][2];  // [buf][mt]

    #pragma unroll
    for (int mt = 0; mt < 2; ++mt) {
        G1[0][mt].q = *(const uint4*)(px1[mt] + 0 * 32);
        G2[0][mt].q = *(const uint4*)(px2[mt] + 0 * 32);
        G1[1][mt].q = *(const uint4*)(px1[mt] + 1 * 32);
        G2[1][mt].q = *(const uint4*)(px2[mt] + 1 * 32);
    }

    const f16x8 zero8 = (f16x8){0, 0, 0, 0, 0, 0, 0, 0};

    __syncthreads();  // w2s half 0 staged

    // kk 0..3 on k-half 0
    #pragma unroll
    for (int kk = 0; kk < 4; ++kk) {
        const int buf = kk & 1;
        f16x8 af[2];
        #pragma unroll
        for (int mt = 0; mt < 2; ++mt) {
            f16x8 sum = G1[buf][mt].h + G2[buf][mt].h;
            af[mt] = __builtin_elementwise_max(sum, zero8);
        }
        #pragma unroll
        for (int mt = 0; mt < 2; ++mt) {   // loads kk 2,3,4,5
            G1[buf][mt].q = *(const uint4*)(px1[mt] + (kk + 2) * 32);
            G2[buf][mt].q = *(const uint4*)(px2[mt] + (kk + 2) * 32);
        }
        #pragma unroll
        for (int tt = 0; tt < 6; ++tt) {
            f16x8 bf = *(const f16x8*)&w2s[(tt * 16 + l16) * W2_STRIDE + kk * 32 + quad * 8];
            acc[0][tt] = __builtin_amdgcn_mfma_f32_16x16x32_f16(af[0], bf, acc[0][tt], 0, 0, 0);
            acc[1][tt] = __builtin_amdgcn_mfma_f32_16x16x32_f16(af[1], bf, acc[1][tt], 0, 0, 0);
        }
    }

    __syncthreads();   // all waves done reading k-half 0
    stageW2(1);
    __syncthreads();   // half 1 staged

    // kk 4..7 on k-half 1
    #pragma unroll
    for (int kk = 4; kk < 8; ++kk) {
        const int buf = kk & 1;
        f16x8 af[2];
        #pragma unroll
        for (int mt = 0; mt < 2; ++mt) {
            f16x8 sum = G1[buf][mt].h + G2[buf][mt].h;
            af[mt] = __builtin_elementwise_max(sum, zero8);
        }
        if (kk < 6) {
            #pragma unroll
            for (int mt = 0; mt < 2; ++mt) {
                G1[buf][mt].q = *(const uint4*)(px1[mt] + (kk + 2) * 32);
                G2[buf][mt].q = *(const uint4*)(px2[mt] + (kk + 2) * 32);
            }
        }
        #pragma unroll
        for (int tt = 0; tt < 6; ++tt) {
            f16x8 bf = *(const f16x8*)&w2s[(tt * 16 + l16) * W2_STRIDE + (kk - 4) * 32 + quad * 8];
            acc[0][tt] = __builtin_amdgcn_mfma_f32_16x16x32_f16(af[0], bf, acc[0][tt], 0, 0, 0);
            acc[1][tt] = __builtin_amdgcn_mfma_f32_16x16x32_f16(af[1], bf, acc[1][tt], 0, 0, 0);
        }
    }

    // payoff-dump precompute (kept out of the hot loop; short live range)
    float b2v[6];
    #pragma unroll
    for (int tt = 0; tt < 6; ++tt) b2v[tt] = b2[tt * 16 + l16];

    int d6[6];
    float pscale[6];
    {
        const int s_ = quad >> 1;
        #pragma unroll
        for (int tt = 0; tt < 6; ++tt) {
            int n = tt * 16 + l16;
            int rr = n / 24;
            int rem = n - rr * 24;
            int c01 = (rem >= 12) ? 1 : 0;
            int a = rem - c01 * 12;
            int k8 = s_ * 4 + rr;
            int toL = (c01 == s_) ? 1 : 0;
            d6[tt] = (toL ? 0 : 1024) + (quad & 1) * 512 + a * 8 + k8;
            pscale[tt] = toL ? 0.5f : 1.0f;   // fold the 0.5 into the L side
        }
    }

    __syncthreads();  // all waves done with w2s; LDS repurposed per-wave

    // per-wave payoff region: [mt][2 sides][8 pp][16 rows][8 k8] f16 = 8 KB/wave
    f16* pw = (f16*)smem + waveId * 4096;
    #pragma unroll
    for (int mt = 0; mt < 2; ++mt) {
        f16* pm = pw + mt * 2048;
        // dump p (+b2, x pscale) as f16 into [side][pp][row][k8]
        #pragma unroll
        for (int tt = 0; tt < 6; ++tt) {
            #pragma unroll
            for (int r = 0; r < 4; ++r)
                pm[d6[tt] + r * 128] = (_Float16)((acc[mt][tt][r] + b2v[tt]) * pscale[tt]);
        }
        // one MFMA per pair: D[i][j] = sum_k8 L[i][k8]*R[j][k8]
        #pragma unroll
        for (int pp = 0; pp < 8; ++pp) {
            f16x8 afp = zero8, bfp = zero8;
            if (quad == 0) {
                afp = *(const f16x8*)&pm[pp * 128 + l16 * 8];
                bfp = *(const f16x8*)&pm[1024 + pp * 128 + l16 * 8];
            }
            f32x4 d = __builtin_amdgcn_mfma_f32_16x16x32_f16(
                afp, bfp, (f32x4){0.f, 0.f, 0.f, 0.f}, 0, 0, 0);
            if (l16 < 12 && quad < 3) {
                float* ob = out + (pairBase + mt * 8 + pp) * 144 + quad * 48 + l16;
                #pragma unroll
                for (int r = 0; r < 4; ++r) ob[r * 12] = d[r];
            }
        }
    }
}

extern "C" void kernel_launch(void* const* d_in, const int* in_sizes, int n_in,
                              void* d_out, int out_size, void* d_ws, size_t ws_size,
                              hipStream_t stream) {
    const float* hidden = (const float*)d_in[0];
    const float* W1 = (const float*)d_in[1];
    const float* b1 = (const float*)d_in[2];
    const float* W2 = (const float*)d_in[3];
    const float* b2 = (const float*)d_in[4];
    const int* e_f = (const int*)d_in[5];
    const int* e_t = (const int*)d_in[6];
    float* out = (float*)d_out;

    char* ws = (char*)d_ws;
    f16* X = (f16*)ws;                              // X1 then X2, 4 MB each
    f16* w2h = (f16*)(ws + 8 * 1024 * 1024);        // W2 f16 image [2][96][152] (+overrun slop)

    x_kernel<<<513, 256, 0, stream>>>(hidden, W1, b1, X, W2, w2h);
    gemm_payoff_kernel<<<1984, 256, 0, stream>>>(X, X + 8192 * 256, e_f, e_t, w2h, b2, out);
}

// Round 3
// 136.400 us; speedup vs baseline: 1.0585x; 1.0376x over previous
//
#include <hip/hip_runtime.h>

typedef unsigned int uint;
typedef _Float16 f16;

typedef __attribute__((ext_vector_type(8))) _Float16 f16x8;
typedef __attribute__((ext_vector_type(2))) _Float16 f16x2;
typedef __attribute__((ext_vector_type(4))) float f32x4;

#define E_CNT 496

// W2 f16 image geometry (stride 136 f16 = 272 B: 16B-aligned rows, bank-friendly)
#define W2_STRIDE 136
#define W2_HALF_F16 (96 * W2_STRIDE)      // 13056
#define W2_HALF_BYTES (W2_HALF_F16 * 2)   // 26112
#define W2_CHUNKS 26                      // 26 x 1KB covers 26112 (+512B slop)
#define LDS_BYTES 26624

// payoff per-wave region: [2 sides][8 pp][136 f16 pp-stride] = 2176 f16 = 4352 B
#define PP_STRIDE 136
#define V_OFF 1088
#define PW_F16 2176

__device__ __forceinline__ uint pack2_f16(float lo, float hi) {
    union { f16x2 h; uint u; } r;
    r.h[0] = (_Float16)lo;
    r.h[1] = (_Float16)hi;
    return r.u;
}

__device__ __forceinline__ void load_lds16(const void* g, void* l) {
    __builtin_amdgcn_global_load_lds(
        (const __attribute__((address_space(1))) void*)g,
        (__attribute__((address_space(3))) void*)l, 16, 0, 0);
}

// ---------------- X staging via swapped-operand MFMA; W1 frags in registers --
// grid = 513; blocks 0..511 = 128 rowblocks x 4 ngroups; block 512 converts W2.
__global__ __launch_bounds__(256) void x_kernel(
    const float* __restrict__ hidden, const float* __restrict__ W1,
    const float* __restrict__ b1, f16* __restrict__ Xout,
    const float* __restrict__ W2, f16* __restrict__ w2h) {
    __shared__ __align__(16) float hs[64 * 132];

    const int tid = threadIdx.x;

    if (blockIdx.x == 512) {
        // convert W2 f32 [96][256] -> f16 image [2][96][W2_STRIDE]
        #pragma unroll
        for (int j = 0; j < 24; ++j) {
            int idx4 = tid + j * 256;       // float4 index 0..6143
            int n = idx4 >> 6;
            int k = (idx4 & 63) << 2;
            int h = k >> 7;
            int kin = k & 127;
            float4 v = *(const float4*)&W2[n * 256 + k];
            uint2 o;
            o.x = pack2_f16(v.x, v.y);
            o.y = pack2_f16(v.z, v.w);
            *(uint2*)&w2h[h * W2_HALF_F16 + n * W2_STRIDE + kin] = o;
        }
        return;
    }

    const int rowblock = blockIdx.x >> 2;
    const int g = blockIdx.x & 3;
    const int ln = tid & 63;
    const int waveId = tid >> 6;
    const int quad = ln >> 4;
    const int l16 = ln & 15;
    const int row0 = rowblock * 64;

    union FU { uint u[4]; f16x8 v; };
    FU wf[2][4];
    float bh[2][4];
    #pragma unroll
    for (int nt = 0; nt < 2; ++nt) {
        const int t = (g * 4 + waveId) * 2 + nt;
        const int half = t >> 4;
        const int htile = t & 15;
        const float* wrow = W1 + (htile * 16 + l16) * 256 + half * 128 + quad * 8;
        #pragma unroll
        for (int kk = 0; kk < 4; ++kk) {
            float4 v0 = *(const float4*)(wrow + kk * 32);
            float4 v1 = *(const float4*)(wrow + kk * 32 + 4);
            wf[nt][kk].u[0] = pack2_f16(v0.x, v0.y);
            wf[nt][kk].u[1] = pack2_f16(v0.z, v0.w);
            wf[nt][kk].u[2] = pack2_f16(v1.x, v1.y);
            wf[nt][kk].u[3] = pack2_f16(v1.z, v1.w);
        }
        #pragma unroll
        for (int r = 0; r < 4; ++r)
            bh[nt][r] = 0.5f * b1[htile * 16 + quad * 4 + r];  // each half adds 0.5*b1
    }

    {
        const float* src = hidden + row0 * 128;
        #pragma unroll
        for (int it = 0; it < 8; ++it) {
            int idx = it * 256 + tid;
            int r = idx >> 5;
            int c4 = idx & 31;
            float4 v = *(const float4*)(src + idx * 4);
            *(float4*)&hs[r * 132 + c4 * 4] = v;
        }
    }
    __syncthreads();

    #pragma unroll
    for (int ch = 0; ch < 4; ++ch) {
        FU hf[4];
        const float* hrow = &hs[(ch * 16 + l16) * 132 + quad * 8];
        #pragma unroll
        for (int kk = 0; kk < 4; ++kk) {
            float4 v0 = *(const float4*)(hrow + kk * 32);
            float4 v1 = *(const float4*)(hrow + kk * 32 + 4);
            hf[kk].u[0] = pack2_f16(v0.x, v0.y);
            hf[kk].u[1] = pack2_f16(v0.z, v0.w);
            hf[kk].u[2] = pack2_f16(v1.x, v1.y);
            hf[kk].u[3] = pack2_f16(v1.z, v1.w);
        }
        #pragma unroll
        for (int nt = 0; nt < 2; ++nt) {
            const int t = (g * 4 + waveId) * 2 + nt;
            const int half = t >> 4;
            const int htile = t & 15;
            f32x4 acc = (f32x4){0.f, 0.f, 0.f, 0.f};
            #pragma unroll
            for (int kk = 0; kk < 4; ++kk)
                acc = __builtin_amdgcn_mfma_f32_16x16x32_f16(wf[nt][kk].v, hf[kk].v, acc, 0, 0, 0);
            uint2 o;
            o.x = pack2_f16(acc[0] + bh[nt][0], acc[1] + bh[nt][1]);
            o.y = pack2_f16(acc[2] + bh[nt][2], acc[3] + bh[nt][3]);
            f16* dst = Xout + half * (8192 * 256)
                     + (row0 + ch * 16 + l16) * 256 + htile * 16 + quad * 4;
            *(uint2*)dst = o;
        }
    }
}

// ---------------- fused GEMM2 (MFMA, fp16) + MFMA payoff ----------------
// block = 256 thr = 4 waves; 64 pairs/block; grid 1984 XCD-swizzled.
// Sequential-mt: acc[6] only (24 acc regs) -> ~6 waves/SIMD; W2 halves restaged
// per mt via global_load_lds from the L2-resident f16 image. LDS 26.6 KB ->
// 6 blocks/CU. Payoff MFMA with swapped operands -> coalesced float4 stores.
__global__ __launch_bounds__(256) void gemm_payoff_kernel(
    const f16* __restrict__ X1, const f16* __restrict__ X2,
    const int* __restrict__ e_f, const int* __restrict__ e_t,
    const f16* __restrict__ w2g, const float* __restrict__ b2,
    float* __restrict__ out) {

    __shared__ __align__(16) unsigned char smem[LDS_BYTES];
    f16* w2s = (f16*)smem;

    const int tid = threadIdx.x;
    const int ln = tid & 63;
    const int waveId = tid >> 6;
    const int quad = ln >> 4;
    const int l16 = ln & 15;
    const int pl = l16 & 7;
    const int s = l16 >> 3;

    // XCD swizzle: 1984 = 8 * 248 (bijective)
    const int bx = blockIdx.x;
    const int lb = (bx & 7) * 248 + (bx >> 3);

    // stage one W2 k-half via async direct-to-LDS (wave-uniform dest, lane x 16B)
    auto stageW2 = [&](int h) {
        const unsigned char* src = (const unsigned char*)w2g + h * W2_HALF_BYTES + ln * 16;
        #pragma unroll
        for (int j = 0; j < 7; ++j) {
            int i = waveId + j * 4;
            if (i < W2_CHUNKS)
                load_lds16(src + i * 1024, smem + i * 1024);
        }
    };

    stageW2(0);   // async; overlapped with setup below

    // edge dtype detect (uniform -> scalar loads)
    bool f64 = true, t64 = true;
    #pragma unroll
    for (int i = 0; i < 16; ++i) {
        if (e_f[2 * i + 1] != 0) f64 = false;
        if (e_t[2 * i + 1] != 0) t64 = false;
    }

    const int pairBase = lb * 64 + waveId * 16;
    const f16* px1[2];
    const f16* px2[2];
    #pragma unroll
    for (int mt = 0; mt < 2; ++mt) {
        int pair = pairBase + mt * 8 + pl;
        int b = pair / E_CNT;
        int e = pair - b * E_CNT;
        int f = f64 ? e_f[2 * e] : e_f[e];
        int t = t64 ? e_t[2 * e] : e_t[e];
        int n1 = s ? t : f;
        int n2 = s ? f : t;
        px1[mt] = X1 + ((b * 32 + n1) * 256 + quad * 8);
        px2[mt] = X2 + ((b * 32 + n2) * 256 + quad * 8);
    }

    // payoff-dump precompute (mt-invariant)
    float b2v[6];
    #pragma unroll
    for (int tt = 0; tt < 6; ++tt) b2v[tt] = b2[tt * 16 + l16];

    int d6[6];
    float psc[6];
    {
        const int s_ = quad >> 1;
        #pragma unroll
        for (int tt = 0; tt < 6; ++tt) {
            int n = tt * 16 + l16;
            int rr = n / 24;
            int rem = n - rr * 24;
            int c01 = (rem >= 12) ? 1 : 0;
            int a = rem - c01 * 12;
            int k8 = s_ * 4 + rr;
            int toL = (c01 == s_) ? 1 : 0;
            d6[tt] = (toL ? 0 : V_OFF) + (quad & 1) * 4 * PP_STRIDE + a * 8 + k8;
            psc[tt] = toL ? 0.5f : 1.0f;   // fold the 0.5 into the U (left) side
        }
    }

    const f16x8 zero8 = (f16x8){0, 0, 0, 0, 0, 0, 0, 0};
    f16* pm = (f16*)smem + waveId * PW_F16;   // per-wave payoff region (overlay)

    typedef union { uint4 q; f16x8 h; } XU;

    #pragma unroll
    for (int mt = 0; mt < 2; ++mt) {
        f32x4 acc[6];
        #pragma unroll
        for (int tt = 0; tt < 6; ++tt) acc[tt] = (f32x4){0.f, 0.f, 0.f, 0.f};

        XU G1[2], G2[2];
        G1[0].q = *(const uint4*)(px1[mt] + 0 * 32);
        G2[0].q = *(const uint4*)(px2[mt] + 0 * 32);
        G1[1].q = *(const uint4*)(px1[mt] + 1 * 32);
        G2[1].q = *(const uint4*)(px2[mt] + 1 * 32);

        __syncthreads();   // W2 half 0 staged (initial stage or restage)

        #pragma unroll
        for (int kk = 0; kk < 4; ++kk) {
            const int buf = kk & 1;
            f16x8 sum = G1[buf].h + G2[buf].h;
            f16x8 af = __builtin_elementwise_max(sum, zero8);
            G1[buf].q = *(const uint4*)(px1[mt] + (kk + 2) * 32);   // loads kk 2..5
            G2[buf].q = *(const uint4*)(px2[mt] + (kk + 2) * 32);
            #pragma unroll
            for (int tt = 0; tt < 6; ++tt) {
                f16x8 bf = *(const f16x8*)&w2s[(tt * 16 + l16) * W2_STRIDE + kk * 32 + quad * 8];
                acc[tt] = __builtin_amdgcn_mfma_f32_16x16x32_f16(af, bf, acc[tt], 0, 0, 0);
            }
        }

        __syncthreads();   // all waves done reading half 0
        stageW2(1);
        __syncthreads();   // half 1 staged

        #pragma unroll
        for (int kk = 4; kk < 8; ++kk) {
            const int buf = kk & 1;
            f16x8 sum = G1[buf].h + G2[buf].h;
            f16x8 af = __builtin_elementwise_max(sum, zero8);
            if (kk < 6) {
                G1[buf].q = *(const uint4*)(px1[mt] + (kk + 2) * 32);
                G2[buf].q = *(const uint4*)(px2[mt] + (kk + 2) * 32);
            }
            #pragma unroll
            for (int tt = 0; tt < 6; ++tt) {
                f16x8 bf = *(const f16x8*)&w2s[(tt * 16 + l16) * W2_STRIDE + (kk - 4) * 32 + quad * 8];
                acc[tt] = __builtin_amdgcn_mfma_f32_16x16x32_f16(af, bf, acc[tt], 0, 0, 0);
            }
        }

        __syncthreads();   // all waves done reading half 1; safe to overlay payoff

        // dump p (+b2, x psc) as f16 into [side][pp][i*8+k8] with pp-stride 136
        #pragma unroll
        for (int tt = 0; tt < 6; ++tt) {
            #pragma unroll
            for (int r = 0; r < 4; ++r)
                pm[d6[tt] + r * PP_STRIDE] = (_Float16)((acc[tt][r] + b2v[tt]) * psc[tt]);
        }

        // payoff: one MFMA per pair, A = V (j rows), B = U (i rows)
        // -> D[col=l16=i][row=quad*4+r=j] -> coalesced float4 stores
        #pragma unroll
        for (int pp = 0; pp < 8; ++pp) {
            f16x8 afp = zero8, bfp = zero8;
            if (quad == 0) {
                afp = *(const f16x8*)&pm[V_OFF + pp * PP_STRIDE + l16 * 8];
                bfp = *(const f16x8*)&pm[pp * PP_STRIDE + l16 * 8];
            }
            f32x4 d = __builtin_amdgcn_mfma_f32_16x16x32_f16(
                afp, bfp, (f32x4){0.f, 0.f, 0.f, 0.f}, 0, 0, 0);
            if (l16 < 12 && quad < 3) {
                float* ob = out + (pairBase + mt * 8 + pp) * 144 + l16 * 12 + quad * 4;
                *(float4*)ob = make_float4(d[0], d[1], d[2], d[3]);
            }
        }

        if (mt == 0) {
            __syncthreads();   // all payoff LDS reads done
            stageW2(0);        // restage half 0 for mt = 1
        }
    }
}

extern "C" void kernel_launch(void* const* d_in, const int* in_sizes, int n_in,
                              void* d_out, int out_size, void* d_ws, size_t ws_size,
                              hipStream_t stream) {
    const float* hidden = (const float*)d_in[0];
    const float* W1 = (const float*)d_in[1];
    const float* b1 = (const float*)d_in[2];
    const float* W2 = (const float*)d_in[3];
    const float* b2 = (const float*)d_in[4];
    const int* e_f = (const int*)d_in[5];
    const int* e_t = (const int*)d_in[6];
    float* out = (float*)d_out;

    char* ws = (char*)d_ws;
    f16* X = (f16*)ws;                              // X1 then X2, 4 MB each
    f16* w2h = (f16*)(ws + 8 * 1024 * 1024);        // W2 f16 image [2][96][136] (+slop)

    x_kernel<<<513, 256, 0, stream>>>(hidden, W1, b1, X, W2, w2h);
    gemm_payoff_kernel<<<1984, 256, 0, stream>>>(X, X + 8192 * 256, e_f, e_t, w2h, b2, out);
}

// Round 4
// 131.609 us; speedup vs baseline: 1.0970x; 1.0364x over previous
//
#include <hip/hip_runtime.h>

typedef unsigned int uint;
typedef _Float16 f16;

typedef __attribute__((ext_vector_type(8))) _Float16 f16x8;
typedef __attribute__((ext_vector_type(2))) _Float16 f16x2;
typedef __attribute__((ext_vector_type(4))) float f32x4;

#define E_CNT 496

// W2 f16 image: [96][264] f16 = 50688 B. Row stride 264 f16 = 132 dwords
// (132 mod 32 = 4 -> quarter-wave b128 frag reads are 2-way = free).
// Staged area padded to 51 KB (51 x 1KB chunks).
#define W2_STRIDE 264
#define W2_F16 (96 * W2_STRIDE)          // 25344
#define W2_STAGE_BYTES 52224             // 51 x 1024 (pad past 50688)
#define W2_CHUNKS 51
#define LDS_BYTES 52224

// payoff per-wave overlay region: [2 sides][8 pp][136 f16] = 2176 f16 = 4352 B
#define PP_STRIDE 136
#define V_OFF 1088
#define PW_F16 2176

__device__ __forceinline__ uint pack2_f16(float lo, float hi) {
    union { f16x2 h; uint u; } r;
    r.h[0] = (_Float16)lo;
    r.h[1] = (_Float16)hi;
    return r.u;
}

__device__ __forceinline__ void load_lds16(const void* g, void* l) {
    __builtin_amdgcn_global_load_lds(
        (const __attribute__((address_space(1))) void*)g,
        (__attribute__((address_space(3))) void*)l, 16, 0, 0);
}

// ---------------- X staging via swapped-operand MFMA; W1 frags in registers --
// grid = 513; blocks 0..511 = 128 rowblocks x 4 ngroups; block 512 converts W2.
__global__ __launch_bounds__(256) void x_kernel(
    const float* __restrict__ hidden, const float* __restrict__ W1,
    const float* __restrict__ b1, f16* __restrict__ Xout,
    const float* __restrict__ W2, f16* __restrict__ w2h) {
    __shared__ __align__(16) float hs[64 * 132];

    const int tid = threadIdx.x;

    if (blockIdx.x == 512) {
        // convert W2 f32 [96][256] -> f16 image [96][264] (pad never read)
        #pragma unroll
        for (int j = 0; j < 24; ++j) {
            int idx4 = tid + j * 256;       // float4 index 0..6143
            int n = idx4 >> 6;
            int k = (idx4 & 63) << 2;
            float4 v = *(const float4*)&W2[n * 256 + k];
            uint2 o;
            o.x = pack2_f16(v.x, v.y);
            o.y = pack2_f16(v.z, v.w);
            *(uint2*)&w2h[n * W2_STRIDE + k] = o;
        }
        return;
    }

    const int rowblock = blockIdx.x >> 2;
    const int g = blockIdx.x & 3;
    const int ln = tid & 63;
    const int waveId = tid >> 6;
    const int quad = ln >> 4;
    const int l16 = ln & 15;
    const int row0 = rowblock * 64;

    union FU { uint u[4]; f16x8 v; };
    FU wf[2][4];
    float bh[2][4];
    #pragma unroll
    for (int nt = 0; nt < 2; ++nt) {
        const int t = (g * 4 + waveId) * 2 + nt;
        const int half = t >> 4;
        const int htile = t & 15;
        const float* wrow = W1 + (htile * 16 + l16) * 256 + half * 128 + quad * 8;
        #pragma unroll
        for (int kk = 0; kk < 4; ++kk) {
            float4 v0 = *(const float4*)(wrow + kk * 32);
            float4 v1 = *(const float4*)(wrow + kk * 32 + 4);
            wf[nt][kk].u[0] = pack2_f16(v0.x, v0.y);
            wf[nt][kk].u[1] = pack2_f16(v0.z, v0.w);
            wf[nt][kk].u[2] = pack2_f16(v1.x, v1.y);
            wf[nt][kk].u[3] = pack2_f16(v1.z, v1.w);
        }
        #pragma unroll
        for (int r = 0; r < 4; ++r)
            bh[nt][r] = 0.5f * b1[htile * 16 + quad * 4 + r];  // each half adds 0.5*b1
    }

    {
        const float* src = hidden + row0 * 128;
        #pragma unroll
        for (int it = 0; it < 8; ++it) {
            int idx = it * 256 + tid;
            int r = idx >> 5;
            int c4 = idx & 31;
            float4 v = *(const float4*)(src + idx * 4);
            *(float4*)&hs[r * 132 + c4 * 4] = v;
        }
    }
    __syncthreads();

    #pragma unroll
    for (int ch = 0; ch < 4; ++ch) {
        FU hf[4];
        const float* hrow = &hs[(ch * 16 + l16) * 132 + quad * 8];
        #pragma unroll
        for (int kk = 0; kk < 4; ++kk) {
            float4 v0 = *(const float4*)(hrow + kk * 32);
            float4 v1 = *(const float4*)(hrow + kk * 32 + 4);
            hf[kk].u[0] = pack2_f16(v0.x, v0.y);
            hf[kk].u[1] = pack2_f16(v0.z, v0.w);
            hf[kk].u[2] = pack2_f16(v1.x, v1.y);
            hf[kk].u[3] = pack2_f16(v1.z, v1.w);
        }
        #pragma unroll
        for (int nt = 0; nt < 2; ++nt) {
            const int t = (g * 4 + waveId) * 2 + nt;
            const int half = t >> 4;
            const int htile = t & 15;
            f32x4 acc = (f32x4){0.f, 0.f, 0.f, 0.f};
            #pragma unroll
            for (int kk = 0; kk < 4; ++kk)
                acc = __builtin_amdgcn_mfma_f32_16x16x32_f16(wf[nt][kk].v, hf[kk].v, acc, 0, 0, 0);
            uint2 o;
            o.x = pack2_f16(acc[0] + bh[nt][0], acc[1] + bh[nt][1]);
            o.y = pack2_f16(acc[2] + bh[nt][2], acc[3] + bh[nt][3]);
            f16* dst = Xout + half * (8192 * 256)
                     + (row0 + ch * 16 + l16) * 256 + htile * 16 + quad * 4;
            *(uint2*)dst = o;
        }
    }
}

// ---------------- fused GEMM2 (MFMA, fp16) + MFMA payoff ----------------
// block = 512 thr = 8 waves; each wave owns 8 pairs; 64 pairs/block;
// grid 1984 XCD-swizzled. W2 staged ONCE (full 50.7 KB image, async
// global_load_lds); K-loop has ZERO internal barriers; 2 barriers total.
__global__ __launch_bounds__(512) void gemm_payoff_kernel(
    const f16* __restrict__ X1, const f16* __restrict__ X2,
    const int* __restrict__ e_f, const int* __restrict__ e_t,
    const f16* __restrict__ w2g, const float* __restrict__ b2,
    float* __restrict__ out) {

    __shared__ __align__(16) unsigned char smem[LDS_BYTES];
    f16* w2s = (f16*)smem;

    const int tid = threadIdx.x;
    const int ln = tid & 63;
    const int waveId = tid >> 6;
    const int quad = ln >> 4;
    const int l16 = ln & 15;
    const int pl = l16 & 7;
    const int s = l16 >> 3;

    // XCD swizzle: 1984 = 8 * 248 (bijective)
    const int bx = blockIdx.x;
    const int lb = (bx & 7) * 248 + (bx >> 3);

    // stage full W2 image once: 51 x 1KB async chunks, wave-strided
    {
        const unsigned char* src = (const unsigned char*)w2g + ln * 16;
        #pragma unroll
        for (int j = 0; j < 7; ++j) {
            int i = waveId + j * 8;
            if (i < W2_CHUNKS)
                load_lds16(src + i * 1024, smem + i * 1024);
        }
    }

    // edge dtype detect (uniform -> scalar loads)
    bool f64 = true, t64 = true;
    #pragma unroll
    for (int i = 0; i < 16; ++i) {
        if (e_f[2 * i + 1] != 0) f64 = false;
        if (e_t[2 * i + 1] != 0) t64 = false;
    }

    const int pairBase = lb * 64 + waveId * 8;
    const f16* px1;
    const f16* px2;
    {
        int pair = pairBase + pl;
        int b = pair / E_CNT;
        int e = pair - b * E_CNT;
        int f = f64 ? e_f[2 * e] : e_f[e];
        int t = t64 ? e_t[2 * e] : e_t[e];
        int n1 = s ? t : f;
        int n2 = s ? f : t;
        px1 = X1 + ((b * 32 + n1) * 256 + quad * 8);
        px2 = X2 + ((b * 32 + n2) * 256 + quad * 8);
    }

    // payoff-dump precompute
    float b2v[6];
    #pragma unroll
    for (int tt = 0; tt < 6; ++tt) b2v[tt] = b2[tt * 16 + l16];

    int d6[6];
    float psc[6];
    {
        const int s_ = quad >> 1;
        #pragma unroll
        for (int tt = 0; tt < 6; ++tt) {
            int n = tt * 16 + l16;
            int rr = n / 24;
            int rem = n - rr * 24;
            int c01 = (rem >= 12) ? 1 : 0;
            int a = rem - c01 * 12;
            int k8 = s_ * 4 + rr;
            int toL = (c01 == s_) ? 1 : 0;
            d6[tt] = (toL ? 0 : V_OFF) + (quad & 1) * 4 * PP_STRIDE + a * 8 + k8;
            psc[tt] = toL ? 0.5f : 1.0f;   // fold the 0.5 into the U (left) side
        }
    }

    f32x4 acc[6];
    #pragma unroll
    for (int tt = 0; tt < 6; ++tt) acc[tt] = (f32x4){0.f, 0.f, 0.f, 0.f};

    typedef union { uint4 q; f16x8 h; } XU;
    XU G1[2], G2[2];
    G1[0].q = *(const uint4*)(px1 + 0 * 32);
    G2[0].q = *(const uint4*)(px2 + 0 * 32);
    G1[1].q = *(const uint4*)(px1 + 1 * 32);
    G2[1].q = *(const uint4*)(px2 + 1 * 32);

    const f16x8 zero8 = (f16x8){0, 0, 0, 0, 0, 0, 0, 0};

    __syncthreads();   // W2 fully staged (compiler drains vmcnt before barrier)

    // all 8 kk, no internal barriers
    #pragma unroll
    for (int kk = 0; kk < 8; ++kk) {
        const int buf = kk & 1;
        f16x8 sum = G1[buf].h + G2[buf].h;
        f16x8 af = __builtin_elementwise_max(sum, zero8);
        if (kk < 6) {
            G1[buf].q = *(const uint4*)(px1 + (kk + 2) * 32);
            G2[buf].q = *(const uint4*)(px2 + (kk + 2) * 32);
        }
        #pragma unroll
        for (int tt = 0; tt < 6; ++tt) {
            f16x8 bf = *(const f16x8*)&w2s[(tt * 16 + l16) * W2_STRIDE + kk * 32 + quad * 8];
            acc[tt] = __builtin_amdgcn_mfma_f32_16x16x32_f16(af, bf, acc[tt], 0, 0, 0);
        }
    }

    __syncthreads();   // all waves done reading W2; overlay per-wave payoff regions

    f16* pm = (f16*)smem + waveId * PW_F16;

    // dump p (+b2, x psc) as f16 into [side][pp][i*8+k8], pp-stride 136
    #pragma unroll
    for (int tt = 0; tt < 6; ++tt) {
        #pragma unroll
        for (int r = 0; r < 4; ++r)
            pm[d6[tt] + r * PP_STRIDE] = (_Float16)((acc[tt][r] + b2v[tt]) * psc[tt]);
    }

    // payoff: one MFMA per pair, A = V (j rows), B = U (i rows)
    // -> D[col=l16=i][row=quad*4+r=j] -> coalesced float4 stores
    #pragma unroll
    for (int pp = 0; pp < 8; ++pp) {
        f16x8 afp = zero8, bfp = zero8;
        if (quad == 0) {
            afp = *(const f16x8*)&pm[V_OFF + pp * PP_STRIDE + l16 * 8];
            bfp = *(const f16x8*)&pm[pp * PP_STRIDE + l16 * 8];
        }
        f32x4 d = __builtin_amdgcn_mfma_f32_16x16x32_f16(
            afp, bfp, (f32x4){0.f, 0.f, 0.f, 0.f}, 0, 0, 0);
        if (l16 < 12 && quad < 3) {
            float* ob = out + (pairBase + pp) * 144 + l16 * 12 + quad * 4;
            *(float4*)ob = make_float4(d[0], d[1], d[2], d[3]);
        }
    }
}

extern "C" void kernel_launch(void* const* d_in, const int* in_sizes, int n_in,
                              void* d_out, int out_size, void* d_ws, size_t ws_size,
                              hipStream_t stream) {
    const float* hidden = (const float*)d_in[0];
    const float* W1 = (const float*)d_in[1];
    const float* b1 = (const float*)d_in[2];
    const float* W2 = (const float*)d_in[3];
    const float* b2 = (const float*)d_in[4];
    const int* e_f = (const int*)d_in[5];
    const int* e_t = (const int*)d_in[6];
    float* out = (float*)d_out;

    char* ws = (char*)d_ws;
    f16* X = (f16*)ws;                              // X1 then X2, 4 MB each
    f16* w2h = (f16*)(ws + 8 * 1024 * 1024);        // W2 f16 image [96][264] + stage slop

    x_kernel<<<513, 256, 0, stream>>>(hidden, W1, b1, X, W2, w2h);
    gemm_payoff_kernel<<<1984, 512, 0, stream>>>(X, X + 8192 * 256, e_f, e_t, w2h, b2, out);
}